// Round 1
// baseline (108.294 us; speedup 1.0000x reference)
//
#include <hip/hip_runtime.h>

#define N_PER_DEG 20000
#define MAX_DEG 10
#define D_FEAT 128
#define N_ATOMS (N_PER_DEG * (MAX_DEG + 1))

// 8 rows per 256-thread block; 32 lanes * float4 = 128 feats per row.
#define ROWS_PER_BLOCK 8
#define BLOCKS_PER_BUCKET (N_PER_DEG / ROWS_PER_BLOCK)   // 2500
#define TOTAL_BLOCKS (BLOCKS_PER_BUCKET * (MAX_DEG + 1)) // 27500

struct AdjPtrs { const int* p[MAX_DEG]; };

__global__ __launch_bounds__(256) void graphpool_kernel(
    const float4* __restrict__ feat,   // [N_ATOMS][32] (float4 view of [N_ATOMS][128])
    AdjPtrs adj,
    float4* __restrict__ out)
{
    const int tid  = threadIdx.x;
    const int lane = tid & 31;                    // feature quad index
    const int row  = blockIdx.x * ROWS_PER_BLOCK + (tid >> 5);

    // Degree is uniform across the whole block (2500 blocks per bucket).
    const int d = blockIdx.x / BLOCKS_PER_BUCKET;

    float4 m = feat[(size_t)row * 32 + lane];

    if (d > 0) {
        const int i = row - d * N_PER_DEG;        // index within bucket
        const int* __restrict__ a = adj.p[d - 1] + (size_t)i * d;
        for (int k = 0; k < d; ++k) {
            const int nb = a[k];
            const float4 v = feat[(size_t)nb * 32 + lane];
            m.x = fmaxf(m.x, v.x);
            m.y = fmaxf(m.y, v.y);
            m.z = fmaxf(m.z, v.z);
            m.w = fmaxf(m.w, v.w);
        }
    }

    out[(size_t)row * 32 + lane] = m;
}

extern "C" void kernel_launch(void* const* d_in, const int* in_sizes, int n_in,
                              void* d_out, int out_size, void* d_ws, size_t ws_size,
                              hipStream_t stream)
{
    const float4* feat = (const float4*)d_in[0];
    // d_in[1] is deg_slice (static layout, hard-coded above)
    AdjPtrs adj;
    for (int d = 1; d <= MAX_DEG; ++d) adj.p[d - 1] = (const int*)d_in[1 + d];
    float4* out = (float4*)d_out;

    graphpool_kernel<<<TOTAL_BLOCKS, 256, 0, stream>>>(feat, adj, out);
}